// Round 4
// baseline (966.610 us; speedup 1.0000x reference)
//
#include <hip/hip_runtime.h>

#define N_NODES 100000
#define N_EDGES 1600000
#define DIM     64
#define HID     256
#define BN_EPS  1e-5f
#define NBUCK   782            // ceil(100000/128) buckets of 128 nodes
#define NCNT    (NBUCK * 8)    // per-(bucket, virtual-XCD) counters
#define NGROUPS 1563           // ceil(100032/64) row-groups for MLP
#define MLP_BLOCKS 521         // 1563 = 3*521: perfectly balanced

typedef short bf16x8 __attribute__((ext_vector_type(8)));
typedef float f32x4  __attribute__((ext_vector_type(4)));

// ws layout (4-byte units):
//   stats  float[128]      @ 0        (sum[64], sumsq[64])  [zeroed]
//   ss     float[128]      @ 128      (scale[64], shift[64])
//   bcnt   int[6256]       @ 256      [zeroed]
//   bbase  int[6257]       @ 6512
//   bcur   int[6256]       @ 12769
//   w1t    bf16[256*64]    @ 19028    [n][k]
//   w2t    bf16[64*256]    @ 27220    [d][k2]
//   ew     int[1600000]    @ 35412    packed: src | (dst&127)<<17
//   xb     bf16[100032*64] @ 1635412  (16B aligned: 1635412*4 % 16 == 0)
// memset covers [0, 6512*4) = stats + ss(harmless) + bcnt

__device__ __forceinline__ unsigned short f2bf(float x) {
    unsigned int u = __float_as_uint(x);
    unsigned int r = (u + 0x7FFFu + ((u >> 16) & 1u)) >> 16;
    return (unsigned short)r;
}

// ---- bucket histogram: LDS pre-reduce, flush to (bucket*8 + blockIdx&7) ----
__global__ __launch_bounds__(256) void k_bcnt(const int* __restrict__ dst,
                                              int* __restrict__ bcnt) {
    __shared__ int lh[NBUCK];
    const int t = threadIdx.x;
    for (int i = t; i < NBUCK; i += 256) lh[i] = 0;
    __syncthreads();
    for (int e = blockIdx.x * 256 + t; e < N_EDGES; e += 256 * 256)
        atomicAdd(&lh[dst[e] >> 7], 1);
    __syncthreads();
    const int vb = blockIdx.x & 7;
    for (int i = t; i < NBUCK; i += 256) {
        int c = lh[i];
        if (c) atomicAdd(&bcnt[i * 8 + vb], c);
    }
}

// ---- single-block scan of 6256 counters -> bases + cursors ----
__global__ __launch_bounds__(1024) void k_bscan(const int* __restrict__ bcnt,
                                                int* __restrict__ bbase,
                                                int* __restrict__ bcur) {
    __shared__ int ps[1024];
    const int t = threadIdx.x;
    const int SEG = 7;                 // 1024*7 >= 6256
    int v[SEG];
    int s = 0;
#pragma unroll
    for (int j = 0; j < SEG; ++j) {
        int idx = t * SEG + j;
        v[j] = (idx < NCNT) ? bcnt[idx] : 0;
        s += v[j];
    }
    ps[t] = s;
    __syncthreads();
    for (int off = 1; off < 1024; off <<= 1) {
        int add = (t >= off) ? ps[t - off] : 0;
        __syncthreads();
        ps[t] += add;
        __syncthreads();
    }
    int run = ps[t] - s;               // exclusive prefix at segment start
#pragma unroll
    for (int j = 0; j < SEG; ++j) {
        int idx = t * SEG + j;
        if (idx < NCNT) { bbase[idx] = run; bcur[idx] = run; run += v[j]; }
    }
    if (t == 1023) bbase[NCNT] = ps[1023];
}

// ---- scatter packed edge words into per-(bucket,vXCD) regions ----
__global__ __launch_bounds__(256) void k_bfill(const int* __restrict__ src,
                                               const int* __restrict__ dst,
                                               int* __restrict__ bcur,
                                               int* __restrict__ ew) {
    const int vb = blockIdx.x & 7;
    for (int e = blockIdx.x * 256 + threadIdx.x; e < N_EDGES; e += 256 * 256) {
        int d = dst[e];
        int s = src[e];
        int pos = atomicAdd(&bcur[(d >> 7) * 8 + vb], 1);
        ew[pos] = s | ((d & 127) << 17);
    }
}

// ---- weight prep: bf16 transposed W1/W2, zero xb pad rows ----
__global__ __launch_bounds__(256) void k_wprep(const float* __restrict__ W1,
                                               const float* __restrict__ W2,
                                               unsigned short* __restrict__ w1t,
                                               unsigned short* __restrict__ w2t,
                                               unsigned short* __restrict__ xb) {
    int id = blockIdx.x * 256 + threadIdx.x;     // 136*256 = 34816
    if (id < 16384) {                            // n*64+k
        int n = id >> 6, k = id & 63;
        w1t[id] = f2bf(W1[k * 256 + n]);
    } else if (id < 32768) {
        int i2 = id - 16384;                     // d*256+k2
        int d = i2 >> 8, k2 = i2 & 255;
        w2t[i2] = f2bf(W2[k2 * 64 + d]);
    } else {
        xb[100000 * 64 + (id - 32768)] = 0;
    }
}

// ---- fused per-bucket gather: LDS f32 accumulate + degree, write bf16 x ----
__global__ __launch_bounds__(256) void k_gms(const float* __restrict__ h,
                                             const int* __restrict__ bbase,
                                             const int* __restrict__ ew,
                                             unsigned short* __restrict__ xb) {
    __shared__ float acc[128 * 64];    // 32 KB
    __shared__ int   ldeg[128];
    __shared__ float invd[128];
    const int b = blockIdx.x;
    const int t = threadIdx.x;
    const int lane = t & 63;
    const int w = t >> 6;

    for (int i = t; i < 128 * 64; i += 256) acc[i] = 0.f;
    if (t < 128) ldeg[t] = 0;
    __syncthreads();

    const int start = bbase[b * 8];
    const int end   = bbase[b * 8 + 8];
    const float* hl = h + lane;

    for (int i0 = start + w * 64; i0 < end; i0 += 256) {
        int idx = i0 + lane;
        int myw = (idx < end) ? ew[idx] : 0;
        int nv = min(64, end - i0);
        int k = 0;
        for (; k + 3 < nv; k += 4) {
            int w0 = __builtin_amdgcn_readlane(myw, k);
            int w1 = __builtin_amdgcn_readlane(myw, k + 1);
            int w2 = __builtin_amdgcn_readlane(myw, k + 2);
            int w3 = __builtin_amdgcn_readlane(myw, k + 3);
            float h0 = hl[(w0 & 0x1FFFF) * 64];
            float h1 = hl[(w1 & 0x1FFFF) * 64];
            float h2 = hl[(w2 & 0x1FFFF) * 64];
            float h3 = hl[(w3 & 0x1FFFF) * 64];
            atomicAdd(&acc[((w0 >> 17) << 6) + lane], h0);
            atomicAdd(&acc[((w1 >> 17) << 6) + lane], h1);
            atomicAdd(&acc[((w2 >> 17) << 6) + lane], h2);
            atomicAdd(&acc[((w3 >> 17) << 6) + lane], h3);
            if (lane == 0) {
                atomicAdd(&ldeg[w0 >> 17], 1);
                atomicAdd(&ldeg[w1 >> 17], 1);
                atomicAdd(&ldeg[w2 >> 17], 1);
                atomicAdd(&ldeg[w3 >> 17], 1);
            }
        }
        for (; k < nv; ++k) {
            int w0 = __builtin_amdgcn_readlane(myw, k);
            float h0 = hl[(w0 & 0x1FFFF) * 64];
            atomicAdd(&acc[((w0 >> 17) << 6) + lane], h0);
            if (lane == 0) atomicAdd(&ldeg[w0 >> 17], 1);
        }
    }
    __syncthreads();
    if (t < 128) invd[t] = 1.0f / (float)max(ldeg[t], 1);
    __syncthreads();

    const int nbase = b * 128;
    for (int i = t; i < 128 * 64; i += 256) {
        int nl = i >> 6, d = i & 63;
        int node = nbase + nl;
        if (node < N_NODES) {
            float x = acc[i] * invd[nl] + h[node * 64 + d];
            xb[node * 64 + d] = f2bf(x);
        }
    }
}

// ---- fused 2-layer MFMA MLP + stats ----
__global__ __launch_bounds__(256, 2) void k_mlp(const unsigned short* __restrict__ xb,
                                                const unsigned short* __restrict__ w1t,
                                                const unsigned short* __restrict__ w2t,
                                                const float* __restrict__ b1,
                                                const float* __restrict__ b2,
                                                float* __restrict__ y,
                                                float* __restrict__ stats) {
    __shared__ unsigned short sW1[256][72];
    __shared__ unsigned short sW2[64][264];
    __shared__ unsigned short sH[4][16][72];
    __shared__ float sB1[256];
    __shared__ float sB2[64];
    const int t = threadIdx.x;
    const int lane = t & 63;
    const int w = t >> 6;
    const int l15 = lane & 15;
    const int g4 = lane >> 4;

    for (int i = t; i < 2048; i += 256) {
        int row = i >> 3, c = i & 7;
        *(uint4*)&sW1[row][c * 8] = *(const uint4*)(w1t + row * 64 + c * 8);
    }
    for (int i = t; i < 2048; i += 256) {
        int row = i >> 5, c = i & 31;
        *(uint4*)&sW2[row][c * 8] = *(const uint4*)(w2t + row * 256 + c * 8);
    }
    sB1[t] = b1[t];
    if (t < 64) sB2[t] = b2[t];
    __syncthreads();

    float lsum[4] = {0.f, 0.f, 0.f, 0.f};
    float lsq[4]  = {0.f, 0.f, 0.f, 0.f};

    for (int g = blockIdx.x; g < NGROUPS; g += MLP_BLOCKS) {
        const int m0 = g * 64 + w * 16;
        const unsigned short* xrow = xb + (size_t)(m0 + l15) * 64 + g4 * 8;
        bf16x8 xf0 = *(const bf16x8*)(xrow);
        bf16x8 xf1 = *(const bf16x8*)(xrow + 32);

        f32x4 oacc[4];
#pragma unroll
        for (int dt = 0; dt < 4; ++dt) oacc[dt] = (f32x4){0.f, 0.f, 0.f, 0.f};

#pragma unroll
        for (int p = 0; p < 4; ++p) {
#pragma unroll
            for (int nt2 = 0; nt2 < 4; ++nt2) {
                const int n0 = p * 64 + nt2 * 16;
                f32x4 hacc = (f32x4){0.f, 0.f, 0.f, 0.f};
                bf16x8 wf0 = *(const bf16x8*)&sW1[n0 + l15][g4 * 8];
                bf16x8 wf1 = *(const bf16x8*)&sW1[n0 + l15][32 + g4 * 8];
                hacc = __builtin_amdgcn_mfma_f32_16x16x32_bf16(wf0, xf0, hacc, 0, 0, 0);
                hacc = __builtin_amdgcn_mfma_f32_16x16x32_bf16(wf1, xf1, hacc, 0, 0, 0);
                float4 bq = *(const float4*)&sB1[n0 + g4 * 4];
                ushort4 pk;
                pk.x = f2bf(fmaxf(hacc[0] + bq.x, 0.f));
                pk.y = f2bf(fmaxf(hacc[1] + bq.y, 0.f));
                pk.z = f2bf(fmaxf(hacc[2] + bq.z, 0.f));
                pk.w = f2bf(fmaxf(hacc[3] + bq.w, 0.f));
                *(ushort4*)&sH[w][l15][nt2 * 16 + g4 * 4] = pk;
            }
#pragma unroll
            for (int s2 = 0; s2 < 2; ++s2) {
                bf16x8 a2 = *(const bf16x8*)&sH[w][l15][s2 * 32 + g4 * 8];
#pragma unroll
                for (int dt = 0; dt < 4; ++dt) {
                    bf16x8 w2f = *(const bf16x8*)&sW2[dt * 16 + l15]
                                                    [p * 64 + s2 * 32 + g4 * 8];
                    oacc[dt] = __builtin_amdgcn_mfma_f32_16x16x32_bf16(
                        a2, w2f, oacc[dt], 0, 0, 0);
                }
            }
        }
#pragma unroll
        for (int dt = 0; dt < 4; ++dt) {
            float bv = sB2[dt * 16 + l15];
#pragma unroll
            for (int r = 0; r < 4; ++r) {
                int mabs = m0 + g4 * 4 + r;
                float val = fmaxf(oacc[dt][r] + bv, 0.f);
                if (mabs < N_NODES) {
                    y[(size_t)mabs * 64 + dt * 16 + l15] = val;
                    lsum[dt] += val;
                    lsq[dt] += val * val;
                }
            }
        }
    }

    __syncthreads();
    float* sred = (float*)&sW1[0][0];
#pragma unroll
    for (int dt = 0; dt < 4; ++dt) {
        sred[t * 8 + dt] = lsum[dt];
        sred[t * 8 + 4 + dt] = lsq[dt];
    }
    __syncthreads();
    if (t < 128) {
        int issq = (t >= 64) ? 4 : 0;
        int d = t & 63;
        int dt = d >> 4, dl = d & 15;
        float a = 0.f;
        for (int i = 0; i < 16; ++i) a += sred[(dl + 16 * i) * 8 + issq + dt];
        atomicAdd(&stats[(issq ? 64 : 0) + d], a);
    }
}

__global__ void k_bnfin(const float* __restrict__ stats,
                        const float* __restrict__ gamma,
                        const float* __restrict__ beta,
                        float* __restrict__ ss) {
    int d = threadIdx.x;
    if (d < 64) {
        const float inv_n = 1.0f / (float)N_NODES;
        float m = stats[d] * inv_n;
        float v = stats[64 + d] * inv_n - m * m;
        float sc = gamma[d] * rsqrtf(v + BN_EPS);
        ss[d] = sc;
        ss[64 + d] = beta[d] - m * sc;
    }
}

__global__ __launch_bounds__(256) void k_apply(const float* __restrict__ ss,
                                               float* __restrict__ out) {
    int i = blockIdx.x * 256 + threadIdx.x;
    if (i >= N_NODES * 16) return;
    float4 v = ((float4*)out)[i];
    int q = i & 15;
    float4 sc = ((const float4*)ss)[q];
    float4 sh = ((const float4*)ss)[16 + q];
    float4 o;
    o.x = fmaf(v.x, sc.x, sh.x);
    o.y = fmaf(v.y, sc.y, sh.y);
    o.z = fmaf(v.z, sc.z, sh.z);
    o.w = fmaf(v.w, sc.w, sh.w);
    ((float4*)out)[i] = o;
}

extern "C" void kernel_launch(void* const* d_in, const int* in_sizes, int n_in,
                              void* d_out, int out_size, void* d_ws, size_t ws_size,
                              hipStream_t stream) {
    const float* h     = (const float*)d_in[0];
    const float* W1    = (const float*)d_in[1];
    const float* b1    = (const float*)d_in[2];
    const float* W2    = (const float*)d_in[3];
    const float* b2    = (const float*)d_in[4];
    const float* gamma = (const float*)d_in[5];
    const float* beta  = (const float*)d_in[6];
    const int*   src   = (const int*)d_in[7];
    const int*   dst   = (const int*)d_in[8];

    int* wsi = (int*)d_ws;
    float*          stats = (float*)(wsi + 0);
    float*          ss    = (float*)(wsi + 128);
    int*            bcnt  = wsi + 256;
    int*            bbase = wsi + 6512;
    int*            bcur  = wsi + 12769;
    unsigned short* w1t   = (unsigned short*)(wsi + 19028);
    unsigned short* w2t   = (unsigned short*)(wsi + 27220);
    int*            ew    = wsi + 35412;
    unsigned short* xb    = (unsigned short*)(wsi + 1635412);
    float*          out   = (float*)d_out;

    hipMemsetAsync(wsi, 0, 6512 * 4, stream);     // stats + ss + bcnt

    k_bcnt<<<256, 256, 0, stream>>>(dst, bcnt);
    k_bscan<<<1, 1024, 0, stream>>>(bcnt, bbase, bcur);
    k_bfill<<<256, 256, 0, stream>>>(src, dst, bcur, ew);
    k_wprep<<<136, 256, 0, stream>>>(W1, W2, w1t, w2t, xb);
    k_gms<<<NBUCK, 256, 0, stream>>>(h, bbase, ew, xb);
    k_mlp<<<MLP_BLOCKS, 256, 0, stream>>>(xb, w1t, w2t, b1, b2, out, stats);
    k_bnfin<<<1, 64, 0, stream>>>(stats, gamma, beta, ss);
    k_apply<<<(N_NODES * 16 + 255) / 256, 256, 0, stream>>>(ss, out);
}

// Round 5
// 889.944 us; speedup vs baseline: 1.0861x; 1.0861x over previous
//
#include <hip/hip_runtime.h>

#define N_NODES 100000
#define N_EDGES 1600000
#define DIM     64
#define HID     256
#define BN_EPS  1e-5f
#define BNODES  64             // nodes per bucket
#define NBUCK   1563           // ceil(100000/64)
#define NCNT    (NBUCK * 8)    // per-(bucket, virtual-XCD) counters = 12504
#define NGROUPS 1563           // row-groups of 64 for MLP
#define MLP_BLOCKS 521         // 1563 = 3*521

typedef short bf16x8 __attribute__((ext_vector_type(8)));
typedef float f32x4  __attribute__((ext_vector_type(4)));

// ws layout (4-byte units):
//   stats  float[128]      @ 0        [zeroed]
//   ss     float[128]      @ 128
//   bcnt   int[12504]      @ 256      [zeroed]
//   bbase  int[12505]      @ 12760
//   bcur   int[12504]      @ 25265
//   w1t    bf16[256*64]    @ 37772    (16B aligned)
//   w2t    bf16[64*256]    @ 45964
//   ew     int[1600000]    @ 54156    packed: src | (dst&63)<<17
//   xb     bf16[100032*64] @ 1654156  (16B aligned)
// memset covers [0, (256+12504)*4) = stats + ss + bcnt

__device__ __forceinline__ unsigned short f2bf(float x) {
    unsigned int u = __float_as_uint(x);
    unsigned int r = (u + 0x7FFFu + ((u >> 16) & 1u)) >> 16;
    return (unsigned short)r;
}

__global__ __launch_bounds__(256) void k_bcnt(const int* __restrict__ dst,
                                              int* __restrict__ bcnt) {
    __shared__ int lh[NBUCK];
    const int t = threadIdx.x;
    for (int i = t; i < NBUCK; i += 256) lh[i] = 0;
    __syncthreads();
    for (int e = blockIdx.x * 256 + t; e < N_EDGES; e += 256 * 256)
        atomicAdd(&lh[dst[e] >> 6], 1);
    __syncthreads();
    const int vb = blockIdx.x & 7;
    for (int i = t; i < NBUCK; i += 256) {
        int c = lh[i];
        if (c) atomicAdd(&bcnt[i * 8 + vb], c);
    }
}

__global__ __launch_bounds__(1024) void k_bscan(const int* __restrict__ bcnt,
                                                int* __restrict__ bbase,
                                                int* __restrict__ bcur) {
    __shared__ int ps[1024];
    const int t = threadIdx.x;
    const int SEG = 13;                // 1024*13 >= 12504
    int v[SEG];
    int s = 0;
#pragma unroll
    for (int j = 0; j < SEG; ++j) {
        int idx = t * SEG + j;
        v[j] = (idx < NCNT) ? bcnt[idx] : 0;
        s += v[j];
    }
    ps[t] = s;
    __syncthreads();
    for (int off = 1; off < 1024; off <<= 1) {
        int add = (t >= off) ? ps[t - off] : 0;
        __syncthreads();
        ps[t] += add;
        __syncthreads();
    }
    int run = ps[t] - s;
#pragma unroll
    for (int j = 0; j < SEG; ++j) {
        int idx = t * SEG + j;
        if (idx < NCNT) { bbase[idx] = run; bcur[idx] = run; run += v[j]; }
    }
    if (t == 1023) bbase[NCNT] = ps[1023];
}

__global__ __launch_bounds__(256) void k_bfill(const int* __restrict__ src,
                                               const int* __restrict__ dst,
                                               int* __restrict__ bcur,
                                               int* __restrict__ ew) {
    const int vb = blockIdx.x & 7;
    for (int e = blockIdx.x * 256 + threadIdx.x; e < N_EDGES; e += 256 * 256) {
        int d = dst[e];
        int s = src[e];
        int pos = atomicAdd(&bcur[(d >> 6) * 8 + vb], 1);
        ew[pos] = s | ((d & 63) << 17);
    }
}

__global__ __launch_bounds__(256) void k_wprep(const float* __restrict__ W1,
                                               const float* __restrict__ W2,
                                               unsigned short* __restrict__ w1t,
                                               unsigned short* __restrict__ w2t,
                                               unsigned short* __restrict__ xb) {
    int id = blockIdx.x * 256 + threadIdx.x;     // 136*256 = 34816
    if (id < 16384) {                            // n*64+k
        int n = id >> 6, k = id & 63;
        w1t[id] = f2bf(W1[k * 256 + n]);
    } else if (id < 32768) {
        int i2 = id - 16384;                     // d*256+k2
        int d = i2 >> 8, k2 = i2 & 255;
        w2t[i2] = f2bf(W2[k2 * 64 + d]);
    } else {
        xb[100000 * 64 + (id - 32768)] = 0;
    }
}

// per-bucket gather: 16-deep-ILP row loads + LDS f32 accumulate, write bf16 x
__global__ __launch_bounds__(256) void k_gms(const float* __restrict__ h,
                                             const int* __restrict__ bbase,
                                             const int* __restrict__ ew,
                                             unsigned short* __restrict__ xb) {
    __shared__ float acc[BNODES * 64];   // 16 KB
    __shared__ int   ldeg[BNODES];
    __shared__ float invd[BNODES];
    const int b = blockIdx.x;
    const int t = threadIdx.x;
    const int lane = t & 63;
    const int w = t >> 6;

    for (int i = t; i < BNODES * 64; i += 256) acc[i] = 0.f;
    if (t < BNODES) ldeg[t] = 0;
    __syncthreads();

    const int start = bbase[b * 8];
    const int end   = bbase[b * 8 + 8];
    const float* hl = h + lane;

    for (int i0 = start + w * 64; i0 < end; i0 += 256) {
        int idx = i0 + lane;
        int valid = (idx < end);
        int myw = valid ? ew[idx] : 0;
        // lane-parallel degree count (one ds op per 64 edges)
        if (valid) atomicAdd(&ldeg[myw >> 17], 1);
        int nv = min(64, end - i0);
        int k = 0;
        for (; k + 15 < nv; k += 16) {
            int wk[16];
            float hv[16];
#pragma unroll
            for (int u = 0; u < 16; ++u)
                wk[u] = __builtin_amdgcn_readlane(myw, k + u);
#pragma unroll
            for (int u = 0; u < 16; ++u)
                hv[u] = hl[(wk[u] & 0x1FFFF) * 64];
#pragma unroll
            for (int u = 0; u < 16; ++u)
                atomicAdd(&acc[((wk[u] >> 17) << 6) + lane], hv[u]);
        }
        for (; k < nv; ++k) {
            int w0 = __builtin_amdgcn_readlane(myw, k);
            float h0 = hl[(w0 & 0x1FFFF) * 64];
            atomicAdd(&acc[((w0 >> 17) << 6) + lane], h0);
        }
    }
    __syncthreads();
    if (t < BNODES) invd[t] = 1.0f / (float)max(ldeg[t], 1);
    __syncthreads();

    const int nbase = b * BNODES;
    for (int i = t; i < BNODES * 64; i += 256) {
        int nl = i >> 6, d = i & 63;
        int node = nbase + nl;
        if (node < N_NODES) {
            float x = acc[i] * invd[nl] + h[node * 64 + d];
            xb[node * 64 + d] = f2bf(x);
        }
    }
}

// fused 2-layer MFMA MLP + stats
__global__ __launch_bounds__(256, 2) void k_mlp(const unsigned short* __restrict__ xb,
                                                const unsigned short* __restrict__ w1t,
                                                const unsigned short* __restrict__ w2t,
                                                const float* __restrict__ b1,
                                                const float* __restrict__ b2,
                                                float* __restrict__ y,
                                                float* __restrict__ stats) {
    __shared__ unsigned short sW1[256][72];
    __shared__ unsigned short sW2[64][264];
    __shared__ unsigned short sH[4][16][72];
    __shared__ float sB1[256];
    __shared__ float sB2[64];
    const int t = threadIdx.x;
    const int lane = t & 63;
    const int w = t >> 6;
    const int l15 = lane & 15;
    const int g4 = lane >> 4;

    for (int i = t; i < 2048; i += 256) {
        int row = i >> 3, c = i & 7;
        *(uint4*)&sW1[row][c * 8] = *(const uint4*)(w1t + row * 64 + c * 8);
    }
    for (int i = t; i < 2048; i += 256) {
        int row = i >> 5, c = i & 31;
        *(uint4*)&sW2[row][c * 8] = *(const uint4*)(w2t + row * 256 + c * 8);
    }
    sB1[t] = b1[t];
    if (t < 64) sB2[t] = b2[t];
    __syncthreads();

    float lsum[4] = {0.f, 0.f, 0.f, 0.f};
    float lsq[4]  = {0.f, 0.f, 0.f, 0.f};

    for (int g = blockIdx.x; g < NGROUPS; g += MLP_BLOCKS) {
        const int m0 = g * 64 + w * 16;
        const unsigned short* xrow = xb + (size_t)(m0 + l15) * 64 + g4 * 8;
        bf16x8 xf0 = *(const bf16x8*)(xrow);
        bf16x8 xf1 = *(const bf16x8*)(xrow + 32);

        f32x4 oacc[4];
#pragma unroll
        for (int dt = 0; dt < 4; ++dt) oacc[dt] = (f32x4){0.f, 0.f, 0.f, 0.f};

#pragma unroll
        for (int p = 0; p < 4; ++p) {
#pragma unroll
            for (int nt2 = 0; nt2 < 4; ++nt2) {
                const int n0 = p * 64 + nt2 * 16;
                f32x4 hacc = (f32x4){0.f, 0.f, 0.f, 0.f};
                bf16x8 wf0 = *(const bf16x8*)&sW1[n0 + l15][g4 * 8];
                bf16x8 wf1 = *(const bf16x8*)&sW1[n0 + l15][32 + g4 * 8];
                hacc = __builtin_amdgcn_mfma_f32_16x16x32_bf16(wf0, xf0, hacc, 0, 0, 0);
                hacc = __builtin_amdgcn_mfma_f32_16x16x32_bf16(wf1, xf1, hacc, 0, 0, 0);
                float4 bq = *(const float4*)&sB1[n0 + g4 * 4];
                ushort4 pk;
                pk.x = f2bf(fmaxf(hacc[0] + bq.x, 0.f));
                pk.y = f2bf(fmaxf(hacc[1] + bq.y, 0.f));
                pk.z = f2bf(fmaxf(hacc[2] + bq.z, 0.f));
                pk.w = f2bf(fmaxf(hacc[3] + bq.w, 0.f));
                *(ushort4*)&sH[w][l15][nt2 * 16 + g4 * 4] = pk;
            }
#pragma unroll
            for (int s2 = 0; s2 < 2; ++s2) {
                bf16x8 a2 = *(const bf16x8*)&sH[w][l15][s2 * 32 + g4 * 8];
#pragma unroll
                for (int dt = 0; dt < 4; ++dt) {
                    bf16x8 w2f = *(const bf16x8*)&sW2[dt * 16 + l15]
                                                    [p * 64 + s2 * 32 + g4 * 8];
                    oacc[dt] = __builtin_amdgcn_mfma_f32_16x16x32_bf16(
                        a2, w2f, oacc[dt], 0, 0, 0);
                }
            }
        }
#pragma unroll
        for (int dt = 0; dt < 4; ++dt) {
            float bv = sB2[dt * 16 + l15];
#pragma unroll
            for (int r = 0; r < 4; ++r) {
                int mabs = m0 + g4 * 4 + r;
                float val = fmaxf(oacc[dt][r] + bv, 0.f);
                if (mabs < N_NODES) {
                    y[(size_t)mabs * 64 + dt * 16 + l15] = val;
                    lsum[dt] += val;
                    lsq[dt] += val * val;
                }
            }
        }
    }

    __syncthreads();
    float* sred = (float*)&sW1[0][0];
#pragma unroll
    for (int dt = 0; dt < 4; ++dt) {
        sred[t * 8 + dt] = lsum[dt];
        sred[t * 8 + 4 + dt] = lsq[dt];
    }
    __syncthreads();
    if (t < 128) {
        int issq = (t >= 64) ? 4 : 0;
        int d = t & 63;
        int dt = d >> 4, dl = d & 15;
        float a = 0.f;
        for (int i = 0; i < 16; ++i) a += sred[(dl + 16 * i) * 8 + issq + dt];
        atomicAdd(&stats[(issq ? 64 : 0) + d], a);
    }
}

__global__ void k_bnfin(const float* __restrict__ stats,
                        const float* __restrict__ gamma,
                        const float* __restrict__ beta,
                        float* __restrict__ ss) {
    int d = threadIdx.x;
    if (d < 64) {
        const float inv_n = 1.0f / (float)N_NODES;
        float m = stats[d] * inv_n;
        float v = stats[64 + d] * inv_n - m * m;
        float sc = gamma[d] * rsqrtf(v + BN_EPS);
        ss[d] = sc;
        ss[64 + d] = beta[d] - m * sc;
    }
}

__global__ __launch_bounds__(256) void k_apply(const float* __restrict__ ss,
                                               float* __restrict__ out) {
    int i = blockIdx.x * 256 + threadIdx.x;
    if (i >= N_NODES * 16) return;
    float4 v = ((float4*)out)[i];
    int q = i & 15;
    float4 sc = ((const float4*)ss)[q];
    float4 sh = ((const float4*)ss)[16 + q];
    float4 o;
    o.x = fmaf(v.x, sc.x, sh.x);
    o.y = fmaf(v.y, sc.y, sh.y);
    o.z = fmaf(v.z, sc.z, sh.z);
    o.w = fmaf(v.w, sc.w, sh.w);
    ((float4*)out)[i] = o;
}

extern "C" void kernel_launch(void* const* d_in, const int* in_sizes, int n_in,
                              void* d_out, int out_size, void* d_ws, size_t ws_size,
                              hipStream_t stream) {
    const float* h     = (const float*)d_in[0];
    const float* W1    = (const float*)d_in[1];
    const float* b1    = (const float*)d_in[2];
    const float* W2    = (const float*)d_in[3];
    const float* b2    = (const float*)d_in[4];
    const float* gamma = (const float*)d_in[5];
    const float* beta  = (const float*)d_in[6];
    const int*   src   = (const int*)d_in[7];
    const int*   dst   = (const int*)d_in[8];

    int* wsi = (int*)d_ws;
    float*          stats = (float*)(wsi + 0);
    float*          ss    = (float*)(wsi + 128);
    int*            bcnt  = wsi + 256;
    int*            bbase = wsi + 12760;
    int*            bcur  = wsi + 25265;
    unsigned short* w1t   = (unsigned short*)(wsi + 37772);
    unsigned short* w2t   = (unsigned short*)(wsi + 45964);
    int*            ew    = wsi + 54156;
    unsigned short* xb    = (unsigned short*)(wsi + 1654156);
    float*          out   = (float*)d_out;

    hipMemsetAsync(wsi, 0, (256 + NCNT) * 4, stream);   // stats + ss + bcnt

    k_bcnt<<<256, 256, 0, stream>>>(dst, bcnt);
    k_bscan<<<1, 1024, 0, stream>>>(bcnt, bbase, bcur);
    k_bfill<<<256, 256, 0, stream>>>(src, dst, bcur, ew);
    k_wprep<<<136, 256, 0, stream>>>(W1, W2, w1t, w2t, xb);
    k_gms<<<NBUCK, 256, 0, stream>>>(h, bbase, ew, xb);
    k_mlp<<<MLP_BLOCKS, 256, 0, stream>>>(xb, w1t, w2t, b1, b2, out, stats);
    k_bnfin<<<1, 64, 0, stream>>>(stats, gamma, beta, ss);
    k_apply<<<(N_NODES * 16 + 255) / 256, 256, 0, stream>>>(ss, out);
}